// Round 4
// baseline (949.238 us; speedup 1.0000x reference)
//
#include <hip/hip_runtime.h>
#include <hip/hip_cooperative_groups.h>
#include <math.h>

namespace cg = cooperative_groups;

// Problem constants (match reference)
#define KB 16      // batch
#define KT 256     // num_tf
#define KG 1024    // num_genes
#define KP 16      // peaks per gene
#define KN 4096    // num_gos
#define KGO 6      // go_dim
#define KH 2       // heads
#define KC 4       // out channels
#define KE 65536   // edges
#define KOUT 32    // num outputs

__device__ __forceinline__ float lrelu(float x, float s) { return x >= 0.f ? x : s * x; }

// ---------------------------------------------------------------------------
// K1 (v4, unchanged — measured good): per-gene subnet
// xcat[b][g] = lrelu(sum_{t,p} x*W + b). Block = (gc of 64 genes, b), 1024
// threads = 4 t-quarters x 256, contiguous 4 KB x segments. XCD swizzle
// groups the 16 b-blocks of a gene-chunk on one XCD. Tail block 256 zeroes
// the CSR histogram + cursors.
// ---------------------------------------------------------------------------
__global__ __launch_bounds__(1024) void k1_subnet(const float* __restrict__ x,
                                                  const float* __restrict__ Wsub,
                                                  const float* __restrict__ bsub,
                                                  float* __restrict__ xcat,
                                                  int* __restrict__ cnt) {
    if (blockIdx.x >= 256) {      // tail block: zero CSR histogram (16 KB)
        int t = threadIdx.x;
#pragma unroll
        for (int i = 0; i < 4; ++i) cnt[t + i * 1024] = 0;
        return;
    }
    int wk  = ((blockIdx.x & 7) << 5) | (blockIdx.x >> 3);  // XCD-group swizzle
    int tid = threadIdx.x;
    int sub = tid >> 8;           // t-quarter 0..3
    int u   = tid & 255;
    int gc  = wk >> 4;            // 0..15  (all 16 b-blocks of gc on one XCD)
    int b   = wk & 15;
    int g0  = gc * 64;
    int g   = g0 + (u >> 2);
    int p4  = (u & 3) * 4;
    const float* xb = x + (size_t)b * (KT * KG * KP) + (size_t)g0 * KP + u * 4;
    const float* wg = Wsub + (size_t)g * (KT * KP) + p4;
    float4 acc = make_float4(0.f, 0.f, 0.f, 0.f);
    int t0 = sub * 64;
#pragma unroll 4
    for (int i = 0; i < 64; ++i) {
        int t = t0 + i;
        float4 xv = *(const float4*)(xb + (size_t)t * (KG * KP));
        float4 wv = *(const float4*)(wg + (size_t)t * KP);
        acc.x += xv.x * wv.x; acc.y += xv.y * wv.y;
        acc.z += xv.z * wv.z; acc.w += xv.w * wv.w;
    }
    float s = acc.x + acc.y + acc.z + acc.w;
    s += __shfl_xor(s, 1, 64);
    s += __shfl_xor(s, 2, 64);    // quad-reduce: 4 lanes of one gene
    __shared__ float part[4][64];
    if ((u & 3) == 0) part[sub][u >> 2] = s;
    __syncthreads();
    if (tid < 64) {
        float v = part[0][tid] + part[1][tid] + part[2][tid] + part[3][tid];
        xcat[b * KG + g0 + tid] = lrelu(v + bsub[g0 + tid], 0.01f);
    }
}

// ---------------------------------------------------------------------------
// K2 (v3, unchanged — measured good): masked fc1 with mask_rep dedup.
// ---------------------------------------------------------------------------
__global__ __launch_bounds__(256) void k2_fc1(const float* __restrict__ w,
                                              const float* __restrict__ mask,
                                              const float* __restrict__ bias,
                                              const float* __restrict__ xcat, // [b][g]
                                              float* __restrict__ ht) {      // [n][b][d]
    int wid = threadIdx.x >> 6;
    int lane = threadIdx.x & 63;
    int b0 = wid * 4;
    float4 xcr[4][4];  // [bb][i] -> x_cat[b0+bb][i*256 + lane*4 .. +3]
#pragma unroll
    for (int bb = 0; bb < 4; ++bb)
#pragma unroll
        for (int i = 0; i < 4; ++i)
            xcr[bb][i] = *(const float4*)(xcat + (b0 + bb) * KG + i * 256 + lane * 4);

    int mj_cur = -1;
    float4 mreg[4];
    for (int r = 0; r < 16; ++r) {
        int j = blockIdx.x * 16 + r;        // row of (w*mask), j < 24576
        int mj = j / 6;                     // mask_rep group (block-uniform)
        if (mj != mj_cur) {
            const float* mr = mask + (size_t)(mj * 6) * KG;  // canonical row
#pragma unroll
            for (int i = 0; i < 4; ++i)
                mreg[i] = *(const float4*)(mr + i * 256 + lane * 4);
            mj_cur = mj;
        }
        const float* wr = w + (size_t)j * KG;
        float acc0 = 0.f, acc1 = 0.f, acc2 = 0.f, acc3 = 0.f;
#pragma unroll
        for (int i = 0; i < 4; ++i) {
            float4 wv = *(const float4*)(wr + i * 256 + lane * 4);
            float4 mv = mreg[i];
            float px = wv.x * mv.x, py = wv.y * mv.y, pz = wv.z * mv.z, pw = wv.w * mv.w;
            acc0 += px * xcr[0][i].x + py * xcr[0][i].y + pz * xcr[0][i].z + pw * xcr[0][i].w;
            acc1 += px * xcr[1][i].x + py * xcr[1][i].y + pz * xcr[1][i].z + pw * xcr[1][i].w;
            acc2 += px * xcr[2][i].x + py * xcr[2][i].y + pz * xcr[2][i].z + pw * xcr[2][i].w;
            acc3 += px * xcr[3][i].x + py * xcr[3][i].y + pz * xcr[3][i].z + pw * xcr[3][i].w;
        }
#pragma unroll
        for (int m = 1; m < 64; m <<= 1) {
            acc0 += __shfl_xor(acc0, m, 64);
            acc1 += __shfl_xor(acc1, m, 64);
            acc2 += __shfl_xor(acc2, m, 64);
            acc3 += __shfl_xor(acc3, m, 64);
        }
        if (lane == 0) {
            float bj = bias[j];
            int d = j >> 12;           // j / N
            int n = j & 4095;          // j % N
            float* hp = ht + ((size_t)n * KB) * KGO + d;
            hp[(b0 + 0) * KGO] = lrelu(acc0 + bj, 0.01f);
            hp[(b0 + 1) * KGO] = lrelu(acc1 + bj, 0.01f);
            hp[(b0 + 2) * KGO] = lrelu(acc2 + bj, 0.01f);
            hp[(b0 + 3) * KGO] = lrelu(acc3 + bj, 0.01f);
        }
    }
}

// ---------------------------------------------------------------------------
// K_TAIL (new): cooperative fusion of former K3, K4a, K4b, K4c, K5, K6.
// All phases are grid-stride loops (correct at any resident grid size);
// per-phase arithmetic / reduction order copied VERBATIM from the separate
// kernels -> identical FP results. grid.sync() between dependent phases
// replaces 5 dispatch boundaries (launch + full drain + ramp each), and the
// single-block scan no longer costs a whole-GPU-idle dispatch.
// ---------------------------------------------------------------------------
__global__ __launch_bounds__(256) void k_tail(const float* __restrict__ ht,
                                              const float* __restrict__ gw,     // [6][8]
                                              const float* __restrict__ att,    // [2][8]
                                              const int*   __restrict__ e32,
                                              const float* __restrict__ gbias,
                                              const float* __restrict__ ow,
                                              const float* __restrict__ obias,
                                              float* __restrict__ hn,           // [n][b][h][c]
                                              float* __restrict__ si,
                                              float* __restrict__ sj,
                                              int* __restrict__ cnt,
                                              int* __restrict__ off,
                                              int* __restrict__ cur,
                                              int* __restrict__ csr,
                                              float* __restrict__ aggr,
                                              float* __restrict__ out) {
    cg::grid_group grid = cg::this_grid();
    const int tid  = threadIdx.x;
    const int bid  = blockIdx.x;
    const int nb   = gridDim.x;
    const int gtid = bid * 256 + tid;
    const int gsz  = nb * 256;

    __shared__ float cgw[48];
    __shared__ float catt[16];
    __shared__ int   smode;
    __shared__ int   sbuf[2][256];
    __shared__ float red[32][4];
    __shared__ float wsum[4];

    // ---- Phase A (= K3): hn / si / sj ------------------------------------
    if (tid < 48) cgw[tid] = gw[tid];
    else if (tid < 64) catt[tid - 48] = att[tid - 48];
    __syncthreads();
    for (int idx = gtid; idx < KN * KB; idx += gsz) {
        float h6[6];
#pragma unroll
        for (int d = 0; d < 6; ++d) h6[d] = ht[(size_t)idx * KGO + d];
        float o[8];
#pragma unroll
        for (int hc = 0; hc < 8; ++hc) {
            float v = 0.f;
#pragma unroll
            for (int d = 0; d < 6; ++d) v += h6[d] * cgw[d * 8 + hc];
            o[hc] = v;
            hn[(size_t)idx * 8 + hc] = v;
        }
#pragma unroll
        for (int hh = 0; hh < 2; ++hh) {
            float vi = 0.f, vj = 0.f;
#pragma unroll
            for (int c = 0; c < 4; ++c) {
                vi += o[hh * 4 + c] * catt[hh * 8 + c];       // att[:, :C]  (x_i)
                vj += o[hh * 4 + c] * catt[hh * 8 + 4 + c];   // att[:, C:]  (x_j)
            }
            si[idx * 2 + hh] = vi;
            sj[idx * 2 + hh] = vj;
        }
    }

    // ---- Phase B (= K4a): histogram with per-chunk dtype vote ------------
    // (independent of Phase A outputs -> no grid sync needed before it)
    for (int base = bid * 256; base < KE; base += gsz) {
        int e = base + tid;
        int hi = e32[2 * e + 1];
        if (tid == 0) smode = 1;
        __syncthreads();
        if (hi != 0) smode = 0;   // benign race: all writers store 0
        __syncthreads();
        int mode = smode;
        int d = mode ? e32[2 * (KE + e)] : e32[KE + e];
        atomicAdd(&cnt[d], 1);
        __syncthreads();          // protect smode before next chunk
    }
    __threadfence();
    grid.sync();

    // ---- Phase C (= K4b): exclusive scan, block 0 only -------------------
    if (bid == 0) {
        int c[16];
        int s = 0;
#pragma unroll
        for (int i = 0; i < 16; ++i) { c[i] = cnt[tid * 16 + i]; s += c[i]; }
        sbuf[0][tid] = s;
        __syncthreads();
        int pb = 0;
        for (int d = 1; d < 256; d <<= 1) {
            int v = sbuf[pb][tid];
            if (tid >= d) v += sbuf[pb][tid - d];
            sbuf[1 - pb][tid] = v;
            pb = 1 - pb;
            __syncthreads();
        }
        int incl = sbuf[pb][tid];
        int run = incl - s;       // exclusive prefix
#pragma unroll
        for (int i = 0; i < 16; ++i) {
            off[tid * 16 + i] = run;
            cur[tid * 16 + i] = run;
            run += c[i];
        }
        if (tid == 255) off[KN] = incl;
    }
    __threadfence();
    grid.sync();

    // ---- Phase D (= K4c): scatter ----------------------------------------
    for (int base = bid * 256; base < KE; base += gsz) {
        int e = base + tid;
        int hi = e32[2 * e + 1];
        if (tid == 0) smode = 1;
        __syncthreads();
        if (hi != 0) smode = 0;
        __syncthreads();
        int mode = smode;
        int d = mode ? e32[2 * (KE + e)] : e32[KE + e];
        int s = mode ? e32[2 * e] : e32[e];
        int p = atomicAdd(&cur[d], 1);
        csr[p] = s;
        __syncthreads();
    }
    __threadfence();
    grid.sync();

    // ---- Phase E (= K5): per-node GAT aggregation ------------------------
    for (int n = bid; n < KN; n += nb) {
        int p = tid >> 3;          // (b,h) pair, 0..31
        int s = tid & 7;
        int b = p >> 1, h = p & 1;
        int o0 = off[n];
        int deg = off[n + 1] - o0;
        float l = 0.f, a0 = 0.f, a1 = 0.f, a2 = 0.f, a3 = 0.f;
        if (deg > 0) {
            float sib = si[(n * KB + b) * 2 + h];
            float m = -1e30f;
            for (int i = s; i < deg; i += 8) {
                int sv = csr[o0 + i];
                float a = sib + sj[(sv * KB + b) * 2 + h];
                a = a >= 0.f ? a : 0.2f * a;
                m = fmaxf(m, a);
            }
            m = fmaxf(m, __shfl_xor(m, 1, 64));
            m = fmaxf(m, __shfl_xor(m, 2, 64));
            m = fmaxf(m, __shfl_xor(m, 4, 64));
            for (int i = s; i < deg; i += 8) {
                int sv = csr[o0 + i];
                float a = sib + sj[(sv * KB + b) * 2 + h];
                a = a >= 0.f ? a : 0.2f * a;
                float wgt = expf(a - m);
                l += wgt;
                float4 hv = *(const float4*)(hn + ((size_t)(sv * KB + b)) * 8 + h * 4);
                a0 += wgt * hv.x; a1 += wgt * hv.y; a2 += wgt * hv.z; a3 += wgt * hv.w;
            }
#pragma unroll
            for (int d = 1; d <= 4; d <<= 1) {
                l  += __shfl_xor(l,  d, 64);
                a0 += __shfl_xor(a0, d, 64);
                a1 += __shfl_xor(a1, d, 64);
                a2 += __shfl_xor(a2, d, 64);
                a3 += __shfl_xor(a3, d, 64);
            }
        }
        if (s == 0) {
            float inv = (deg > 0) ? 1.f / l : 0.f;
            red[p][0] = a0 * inv; red[p][1] = a1 * inv;
            red[p][2] = a2 * inv; red[p][3] = a3 * inv;
        }
        __syncthreads();
        if (tid < 64) {
            int bb = tid >> 2, c = tid & 3;
            float v = gbias[c];
            if (deg > 0)
                v += 0.5f * (red[bb * 2 + 0][c] + red[bb * 2 + 1][c]) / (float)deg;
            aggr[bb * (KC * KN) + c * KN + n] = v;
        }
        __syncthreads();           // protect red[] before next node
    }
    __threadfence();
    grid.sync();

    // ---- Phase F (= K6): readout -----------------------------------------
    for (int pair = bid; pair < KB * KOUT; pair += nb) {
        int b = pair >> 5;
        int k = pair & 31;
        const float* ar = aggr + (size_t)b * (KC * KN);
        const float* wr = ow + (size_t)k * (KC * KN);
        float sum = 0.f;
#pragma unroll 4
        for (int i = 0; i < 16; ++i) {
            int j = (i * 256 + tid) * 4;
            float4 av = *(const float4*)(ar + j);
            float4 wv = *(const float4*)(wr + j);
            av.x = lrelu(av.x, 0.01f); av.y = lrelu(av.y, 0.01f);
            av.z = lrelu(av.z, 0.01f); av.w = lrelu(av.w, 0.01f);
            sum += av.x * wv.x + av.y * wv.y + av.z * wv.z + av.w * wv.w;
        }
#pragma unroll
        for (int d = 32; d > 0; d >>= 1) sum += __shfl_down(sum, d, 64);
        if ((tid & 63) == 0) wsum[tid >> 6] = sum;
        __syncthreads();
        if (tid == 0) out[b * KOUT + k] = wsum[0] + wsum[1] + wsum[2] + wsum[3] + obias[k];
        __syncthreads();           // protect wsum before next pair
    }
}

// ---------------------------------------------------------------------------
extern "C" void kernel_launch(void* const* d_in, const int* in_sizes, int n_in,
                              void* d_out, int out_size, void* d_ws, size_t ws_size,
                              hipStream_t stream) {
    const float* x     = (const float*)d_in[0];
    const int*   e32   = (const int*)d_in[1];
    const float* Wsub  = (const float*)d_in[2];
    const float* bsub  = (const float*)d_in[3];
    const float* fc1w  = (const float*)d_in[4];
    const float* maskr = (const float*)d_in[5];
    const float* fc1b  = (const float*)d_in[6];
    const float* gatw  = (const float*)d_in[7];
    const float* gata  = (const float*)d_in[8];
    const float* gatb  = (const float*)d_in[9];
    const float* outw  = (const float*)d_in[10];
    const float* outb  = (const float*)d_in[11];
    float* out = (float*)d_out;

    // Workspace layout (all 16-float aligned; ~6.5 MB total)
    float* ws   = (float*)d_ws;
    float* xcat = ws;                              // [B][G]        16384
    float* ht   = xcat + KB * KG;                  // [N][B][GO]    393216
    float* hn   = ht + (size_t)KN * KB * KGO;      // [N][B][H][C]  524288
    float* si   = hn + (size_t)KN * KB * KH * KC;  // [N][B][H]     131072
    float* sj   = si + (size_t)KN * KB * KH;       //               131072
    float* aggr = sj + (size_t)KN * KB * KH;       // [B][C][N]     262144
    int* icnt  = (int*)(aggr + (size_t)KB * KC * KN);  // N
    int* ioff  = icnt + KN;                            // N+1 (padded 16)
    int* icur  = ioff + (KN + 16);                     // N
    int* icsr  = icur + KN;                            // E

    // Occupancy-clamped cooperative grid (static-cached; pure query, no
    // stream ops -> graph-capture safe). Grid-stride phases are correct at
    // any grid size <= resident capacity.
    static int g_nblk = 0;
    if (g_nblk == 0) {
        int occ = 0;
        hipOccupancyMaxActiveBlocksPerMultiprocessor(&occ, k_tail, 256, 0);
        if (occ < 1) occ = 1;
        long nb = (long)occ * 256;       // 256 CUs on MI355X
        if (nb > 4096) nb = 4096;
        g_nblk = (int)nb;
    }

    k1_subnet<<<257, 1024, 0, stream>>>(x, Wsub, bsub, xcat, icnt);
    k2_fc1<<<(KN * KGO) / 16, 256, 0, stream>>>(fc1w, maskr, fc1b, xcat, ht);

    void* args[] = {(void*)&ht, (void*)&gatw, (void*)&gata, (void*)&e32,
                    (void*)&gatb, (void*)&outw, (void*)&outb,
                    (void*)&hn, (void*)&si, (void*)&sj,
                    (void*)&icnt, (void*)&ioff, (void*)&icur, (void*)&icsr,
                    (void*)&aggr, (void*)&out};
    hipLaunchCooperativeKernel((const void*)k_tail, dim3(g_nblk), dim3(256),
                               args, 0, stream);
}